// Round 2
// baseline (677.153 us; speedup 1.0000x reference)
//
#include <hip/hip_runtime.h>

typedef float floatx4 __attribute__((ext_vector_type(4)));
typedef __bf16 bf16x2 __attribute__((ext_vector_type(2)));
typedef __bf16 bf16x4 __attribute__((ext_vector_type(4)));
typedef __bf16 bf16x8 __attribute__((ext_vector_type(8)));

#define D_MODEL 1024
#define D_FF 4096
#define NE 8

// ---- async global->LDS, 16B per lane. LDS dest must be lane-linear. ----
__device__ __forceinline__ void gload16(const void* g, void* l) {
    __builtin_amdgcn_global_load_lds(
        (const __attribute__((address_space(1))) void*)g,
        (__attribute__((address_space(3))) void*)l, 16, 0, 0);
}

// Swizzled 32-k subtile: rows x 32 k (bf16). Granule (16B = 8 elems) for
// (row, q) lives at element offset row*32 + ((q ^ ((row>>2)&3))<<3).
__device__ __forceinline__ int frag_off(int row, int q) {
    return row * 32 + ((q ^ ((row >> 2) & 3)) << 3);
}

// pack two fp32 -> one dword of two bf16 (lo = first arg)
__device__ __forceinline__ unsigned int pk(float lo, float hi) {
    union { bf16x2 v; unsigned int u; } c;
    c.v = bf16x2{(__bf16)lo, (__bf16)hi};
    return c.u;
}

// ---------------- router ----------------------------------------------------
__global__ __launch_bounds__(256) void router_kernel(
    const float* __restrict__ x, const float* __restrict__ Wr,
    const float* __restrict__ br, int* __restrict__ cnt,
    int* __restrict__ list, float* __restrict__ w_slot, int T)
{
    int wv = threadIdx.x >> 6;
    int lane = threadIdx.x & 63;
    int t = blockIdx.x * 4 + wv;
    if (t >= T) return;

    const float* xp = x + (size_t)t * D_MODEL;
    float acc[8] = {0.f,0.f,0.f,0.f,0.f,0.f,0.f,0.f};
#pragma unroll
    for (int i = 0; i < 16; ++i) {
        int d = i * 64 + lane;
        float xv = xp[d];
        float4 w0 = *(const float4*)(Wr + d * 8);
        float4 w1 = *(const float4*)(Wr + d * 8 + 4);
        acc[0] += xv * w0.x; acc[1] += xv * w0.y;
        acc[2] += xv * w0.z; acc[3] += xv * w0.w;
        acc[4] += xv * w1.x; acc[5] += xv * w1.y;
        acc[6] += xv * w1.z; acc[7] += xv * w1.w;
    }
#pragma unroll
    for (int off = 32; off >= 1; off >>= 1) {
#pragma unroll
        for (int e = 0; e < 8; ++e)
            acc[e] += __shfl_down(acc[e], off, 64);
    }
    if (lane == 0) {
        float l[8];
#pragma unroll
        for (int e = 0; e < 8; ++e) l[e] = acc[e] + br[e];
        int i0 = 0; float v0 = l[0];
#pragma unroll
        for (int e = 1; e < 8; ++e) if (l[e] > v0) { v0 = l[e]; i0 = e; }
        int i1 = -1; float v1 = -3.4e38f;
#pragma unroll
        for (int e = 0; e < 8; ++e) if (e != i0 && l[e] > v1) { v1 = l[e]; i1 = e; }
        float ex = __expf(v1 - v0);
        float w0 = 1.f / (1.f + ex);
        float w1 = ex / (1.f + ex);
        int p0 = atomicAdd(&cnt[i0], 1);
        list[i0 * T + p0] = 2 * t;
        int p1 = atomicAdd(&cnt[i1], 1);
        list[i1 * T + p1] = 2 * t + 1;
        w_slot[2 * t]     = w0;
        w_slot[2 * t + 1] = w1;
    }
}

// ---------------- fused prep: 3x transpose-convert + x convert ---------------
// blocks [0,8192): Wg, [8192,16384): Wu, [16384,24576): Wd, [24576,25600): x
// 64x64 tile, transpose at dword (bf16x2-along-k) granularity.
// LDS [n=64][kpair=32] dwords, row stride 33 -> conflict-free b32 both ways.
__global__ __launch_bounds__(256) void prep_kernel(
    const float* __restrict__ Wg, const float* __restrict__ Wu,
    const float* __restrict__ Wd, const float* __restrict__ x,
    __bf16* __restrict__ Wgt, __bf16* __restrict__ Wut,
    __bf16* __restrict__ Wdt, __bf16* __restrict__ Xb)
{
    const int bid = blockIdx.x;
    const int tid = threadIdx.x;
    if (bid >= 24576) {
        int base = (bid - 24576) * 2048 + tid * 8;
        float4 v0 = *(const float4*)(x + base);
        float4 v1 = *(const float4*)(x + base + 4);
        bf16x8 o = {(__bf16)v0.x, (__bf16)v0.y, (__bf16)v0.z, (__bf16)v0.w,
                    (__bf16)v1.x, (__bf16)v1.y, (__bf16)v1.z, (__bf16)v1.w};
        *(bf16x8*)(Xb + base) = o;
        return;
    }
    const int tensor = bid >> 13;
    const int rem = bid & 8191;
    const int e = rem >> 10;
    const int tile = rem & 1023;
    const float* src; __bf16* dst; int K, N, kb, nb;
    if (tensor == 0)      { src = Wg; dst = Wgt; }
    else if (tensor == 1) { src = Wu; dst = Wut; }
    else                  { src = Wd; dst = Wdt; }
    if (tensor < 2) { K = 1024; N = 4096; kb = (tile & 15) << 6; nb = (tile >> 4) << 6; }
    else            { K = 4096; N = 1024; kb = (tile & 63) << 6; nb = (tile >> 6) << 6; }
    src += (size_t)e * K * N + (size_t)kb * N + nb;
    dst += (size_t)e * K * N + (size_t)nb * K + kb;

    __shared__ unsigned int tp[64 * 33];

    const int p  = tid >> 3;          // k-pair 0..31 (rows 2p, 2p+1)
    const int ci = tid & 7;           // col quad 0..7
    const float* s0 = src + (size_t)(2 * p) * N + 4 * ci;
    float4 r0a = *(const float4*)(s0);
    float4 r0b = *(const float4*)(s0 + 32);
    float4 r1a = *(const float4*)(s0 + N);
    float4 r1b = *(const float4*)(s0 + N + 32);

    unsigned int* w0 = &tp[(4 * ci) * 33 + p];
    w0[0]  = pk(r0a.x, r1a.x);
    w0[33] = pk(r0a.y, r1a.y);
    w0[66] = pk(r0a.z, r1a.z);
    w0[99] = pk(r0a.w, r1a.w);
    unsigned int* w1 = &tp[(4 * ci + 32) * 33 + p];
    w1[0]  = pk(r0b.x, r1b.x);
    w1[33] = pk(r0b.y, r1b.y);
    w1[66] = pk(r0b.z, r1b.z);
    w1[99] = pk(r0b.w, r1b.w);
    __syncthreads();

    const int r = tid >> 2;           // output n-row 0..63
    const int q = tid & 3;            // quarter of the 64-elem k-row
    const unsigned int* rp = &tp[r * 33 + q * 8];
    uint4 oa = {rp[0], rp[1], rp[2], rp[3]};
    uint4 ob = {rp[4], rp[5], rp[6], rp[7]};
    __bf16* drow = dst + (size_t)r * K + q * 16;
    *(uint4*)(drow)     = oa;
    *(uint4*)(drow + 8) = ob;
}

// ---------------- gate+up GEMM: 128x64 tile, BK=64, 3 blocks/CU --------------
__global__ __launch_bounds__(256, 3) void gateup3_kernel(
    const __bf16* __restrict__ Xb, const __bf16* __restrict__ Wgt,
    const __bf16* __restrict__ Wut, const float* __restrict__ bg,
    const float* __restrict__ bu, const int* __restrict__ cnt,
    const int* __restrict__ list, __bf16* __restrict__ H, int T)
{
    const int e  = blockIdx.z;
    const int m0 = blockIdx.y * 128;
    const int n0 = blockIdx.x * 64;
    const int count = cnt[e];
    if (m0 >= count) return;

    __shared__ __bf16 ldsA[8192];    // 2 subtiles of 128x32
    __shared__ __bf16 ldsBg[4096];   // 2 subtiles of 64x32
    __shared__ __bf16 ldsBu[4096];
    __shared__ int s_entry[128];

    const int tid = threadIdx.x;
    if (tid < 128) {
        int r = m0 + tid;
        s_entry[tid] = (r < count) ? list[e * T + r] : list[e * T];
    }
    __syncthreads();

    // A staging: 4 granules/thread. p -> subtile s=p>>9, row=(p&511)>>2,
    // slot j=p&3, src granule g=j^((row>>2)&3). LDS dest byte = p*16 (linear).
    const __bf16* asrc[4]; char* adst[4];
#pragma unroll
    for (int i = 0; i < 4; ++i) {
        int p = i * 256 + tid;
        int s = p >> 9;
        int row = (p & 511) >> 2, j = p & 3;
        int g = j ^ ((row >> 2) & 3);
        asrc[i] = Xb + (size_t)(s_entry[row] >> 1) * D_MODEL + s * 32 + g * 8;
        adst[i] = (char*)ldsA + p * 16;
    }
    // B staging: 2 granules/thread per tensor.
    const __bf16* gsrc[2]; const __bf16* usrc[2]; char* gdst[2]; char* udst[2];
#pragma unroll
    for (int i = 0; i < 2; ++i) {
        int p = i * 256 + tid;
        int s = p >> 8;
        int row = (p & 255) >> 2, j = p & 3;
        int g = j ^ ((row >> 2) & 3);
        gsrc[i] = Wgt + ((size_t)e * D_FF + n0 + row) * D_MODEL + s * 32 + g * 8;
        usrc[i] = Wut + ((size_t)e * D_FF + n0 + row) * D_MODEL + s * 32 + g * 8;
        gdst[i] = (char*)ldsBg + p * 16;
        udst[i] = (char*)ldsBu + p * 16;
    }

    const int wv = tid >> 6, lane = tid & 63;
    const int wm = wv >> 1, wn = wv & 1;
    const int q = lane >> 4, ln = lane & 15;
    int aoff[4], boff[2];
#pragma unroll
    for (int i = 0; i < 4; ++i) aoff[i] = frag_off(wm * 64 + i * 16 + ln, q);
#pragma unroll
    for (int i = 0; i < 2; ++i) boff[i] = frag_off(wn * 32 + i * 16 + ln, q);

    floatx4 accg[4][2] = {};
    floatx4 accu[4][2] = {};

    for (int k0 = 0; k0 < D_MODEL; k0 += 64) {
#pragma unroll
        for (int i = 0; i < 4; ++i) gload16(asrc[i] + k0, adst[i]);
#pragma unroll
        for (int i = 0; i < 2; ++i) {
            gload16(gsrc[i] + k0, gdst[i]);
            gload16(usrc[i] + k0, udst[i]);
        }
        __syncthreads();

#pragma unroll
        for (int s = 0; s < 2; ++s) {
            bf16x8 af[4], bgf[2], buf[2];
#pragma unroll
            for (int i = 0; i < 4; ++i) af[i]  = *(const bf16x8*)&ldsA[s * 4096 + aoff[i]];
#pragma unroll
            for (int i = 0; i < 2; ++i) bgf[i] = *(const bf16x8*)&ldsBg[s * 2048 + boff[i]];
#pragma unroll
            for (int i = 0; i < 2; ++i) buf[i] = *(const bf16x8*)&ldsBu[s * 2048 + boff[i]];
#pragma unroll
            for (int mi = 0; mi < 4; ++mi)
#pragma unroll
                for (int ni = 0; ni < 2; ++ni) {
                    accg[mi][ni] = __builtin_amdgcn_mfma_f32_16x16x32_bf16(af[mi], bgf[ni], accg[mi][ni], 0, 0, 0);
                    accu[mi][ni] = __builtin_amdgcn_mfma_f32_16x16x32_bf16(af[mi], buf[ni], accu[mi][ni], 0, 0, 0);
                }
        }
        __syncthreads();
    }

#pragma unroll
    for (int ni = 0; ni < 2; ++ni) {
        int col = n0 + wn * 32 + ni * 16 + ln;
        float bgv = bg[e * D_FF + col];
        float buv = bu[e * D_FF + col];
#pragma unroll
        for (int mi = 0; mi < 4; ++mi) {
            int lrow0 = wm * 64 + mi * 16 + q * 4;
#pragma unroll
            for (int r = 0; r < 4; ++r) {
                int lr = lrow0 + r;
                if (m0 + lr < count) {
                    int entry = s_entry[lr];
                    float g = accg[mi][ni][r] + bgv;
                    float u = accu[mi][ni][r] + buv;
                    float h = g / (1.f + __expf(-g)) * u;
                    H[(size_t)entry * D_FF + col] = (__bf16)h;
                }
            }
        }
    }
}

// ---------------- down GEMM: 128x128, BK=64, K-split x4 ----------------------
__global__ __launch_bounds__(256, 3) void down3_kernel(
    const __bf16* __restrict__ H, const __bf16* __restrict__ Wdt,
    const float* __restrict__ bd, const int* __restrict__ cnt,
    const int* __restrict__ list, float* __restrict__ Y, int T)
{
    const int e  = blockIdx.z >> 2;
    const int kc = blockIdx.z & 3;
    const int m0 = blockIdx.y * 128;
    const int n0 = blockIdx.x * 128;
    const int count = cnt[e];
    if (m0 >= count) return;

    __shared__ __bf16 ldsA[8192];    // 2 subtiles of 128x32
    __shared__ __bf16 ldsB[8192];
    __shared__ int s_entry[128];

    const int tid = threadIdx.x;
    if (tid < 128) {
        int r = m0 + tid;
        s_entry[tid] = (r < count) ? list[e * T + r] : list[e * T];
    }
    __syncthreads();

    const int kbase = kc * (D_FF / 4);
    const __bf16* asrc[4]; const __bf16* bsrc[4];
    char* adst[4]; char* bdst[4];
#pragma unroll
    for (int i = 0; i < 4; ++i) {
        int p = i * 256 + tid;
        int s = p >> 9;
        int row = (p & 511) >> 2, j = p & 3;
        int g = j ^ ((row >> 2) & 3);
        asrc[i] = H + (size_t)s_entry[row] * D_FF + kbase + s * 32 + g * 8;
        bsrc[i] = Wdt + ((size_t)e * D_MODEL + n0 + row) * D_FF + kbase + s * 32 + g * 8;
        adst[i] = (char*)ldsA + p * 16;
        bdst[i] = (char*)ldsB + p * 16;
    }

    const int wv = tid >> 6, lane = tid & 63;
    const int wm = wv >> 1, wn = wv & 1;
    const int q = lane >> 4, ln = lane & 15;
    int aoff[4], boff[4];
#pragma unroll
    for (int i = 0; i < 4; ++i) {
        aoff[i] = frag_off(wm * 64 + i * 16 + ln, q);
        boff[i] = frag_off(wn * 64 + i * 16 + ln, q);
    }

    floatx4 acc[4][4] = {};

    for (int k0 = 0; k0 < D_FF / 4; k0 += 64) {
#pragma unroll
        for (int i = 0; i < 4; ++i) {
            gload16(asrc[i] + k0, adst[i]);
            gload16(bsrc[i] + k0, bdst[i]);
        }
        __syncthreads();

#pragma unroll
        for (int s = 0; s < 2; ++s) {
            bf16x8 af[4], bf[4];
#pragma unroll
            for (int i = 0; i < 4; ++i) af[i] = *(const bf16x8*)&ldsA[s * 4096 + aoff[i]];
#pragma unroll
            for (int i = 0; i < 4; ++i) bf[i] = *(const bf16x8*)&ldsB[s * 4096 + boff[i]];
#pragma unroll
            for (int mi = 0; mi < 4; ++mi)
#pragma unroll
                for (int ni = 0; ni < 4; ++ni)
                    acc[mi][ni] = __builtin_amdgcn_mfma_f32_16x16x32_bf16(af[mi], bf[ni], acc[mi][ni], 0, 0, 0);
        }
        __syncthreads();
    }

    const size_t kc_off = (size_t)kc * 2 * T * D_MODEL;
#pragma unroll
    for (int ni = 0; ni < 4; ++ni) {
        int col = n0 + wn * 64 + ni * 16 + ln;
        float bdv = (kc == 0) ? bd[e * D_MODEL + col] : 0.f;
#pragma unroll
        for (int mi = 0; mi < 4; ++mi) {
            int lrow0 = wm * 64 + mi * 16 + q * 4;
#pragma unroll
            for (int r = 0; r < 4; ++r) {
                int lr = lrow0 + r;
                if (m0 + lr < count) {
                    int entry = s_entry[lr];
                    Y[kc_off + (size_t)entry * D_MODEL + col] = acc[mi][ni][r] + bdv;
                }
            }
        }
    }
}

// ---------------- combine: out[t] = w0*sum_kc Y[kc][2t] + w1*sum_kc Y[kc][2t+1]
__global__ __launch_bounds__(256) void combine_kernel(
    const float* __restrict__ Y, const float* __restrict__ w_slot,
    float* __restrict__ out, int T)
{
    int idx = blockIdx.x * 256 + threadIdx.x;      // over T*D/4
    int t = idx >> 8;                               // D/4 = 256
    const float4* Y4 = (const float4*)Y;
    size_t r0 = (size_t)(2 * t) * 256 + (idx & 255);
    size_t r1 = r0 + 256;
    size_t ks = (size_t)2 * T * 256;
    float4 a = Y4[r0], b = Y4[r1];
#pragma unroll
    for (int kc = 1; kc < 4; ++kc) {
        float4 va = Y4[r0 + kc * ks], vb = Y4[r1 + kc * ks];
        a.x += va.x; a.y += va.y; a.z += va.z; a.w += va.w;
        b.x += vb.x; b.y += vb.y; b.z += vb.z; b.w += vb.w;
    }
    float w0 = w_slot[2 * t], w1 = w_slot[2 * t + 1];
    float4 o = {w0 * a.x + w1 * b.x, w0 * a.y + w1 * b.y,
                w0 * a.z + w1 * b.z, w0 * a.w + w1 * b.w};
    ((float4*)out)[idx] = o;
}

// ============================================================================
extern "C" void kernel_launch(void* const* d_in, const int* in_sizes, int n_in,
                              void* d_out, int out_size, void* d_ws, size_t ws_size,
                              hipStream_t stream) {
    const float* x  = (const float*)d_in[0];
    const float* Wr = (const float*)d_in[1];
    const float* br = (const float*)d_in[2];
    const float* Wg = (const float*)d_in[3];
    const float* bg = (const float*)d_in[4];
    const float* Wu = (const float*)d_in[5];
    const float* bu = (const float*)d_in[6];
    const float* Wd = (const float*)d_in[7];
    const float* bd = (const float*)d_in[8];
    float* out = (float*)d_out;
    const int T = in_sizes[0] / D_MODEL;   // 2048

    char* ws = (char*)d_ws;
    size_t off = 256;
    int*   cnt    = (int*)ws;
    int*   list   = (int*)(ws + off);              off += (size_t)NE * T * 4;
    float* w_slot = (float*)(ws + off);            off += (size_t)2 * T * 4;
    off = (off + 1023) & ~(size_t)1023;
    __bf16* Xb  = (__bf16*)(ws + off);             off += (size_t)T * D_MODEL * 2;
    __bf16* H   = (__bf16*)(ws + off);             off += (size_t)2 * T * D_FF * 2;
    __bf16* Wgt = (__bf16*)(ws + off);
    float*  Y   = (float*)(ws + off);              // aliases Wgt (dead after gateup)
    off += (size_t)NE * D_MODEL * D_FF * 2;        // 67.1 MB == Y's 67.1 MB (kc=4)
    __bf16* Wut = (__bf16*)(ws + off);             off += (size_t)NE * D_MODEL * D_FF * 2;
    __bf16* Wdt = (__bf16*)(ws + off);             off += (size_t)NE * D_FF * D_MODEL * 2;

    hipMemsetAsync(cnt, 0, 256, stream);

    router_kernel<<<dim3((T + 3) / 4), dim3(256), 0, stream>>>(x, Wr, br, cnt, list, w_slot, T);

    prep_kernel<<<dim3(25600), dim3(256), 0, stream>>>(Wg, Wu, Wd, x, Wgt, Wut, Wdt, Xb);

    dim3 gb(D_FF / 64, (T + 127) / 128, NE);
    gateup3_kernel<<<gb, dim3(256), 0, stream>>>(Xb, Wgt, Wut, bg, bu, cnt, list, H, T);

    dim3 gc(D_MODEL / 128, (T + 127) / 128, NE * 4);
    down3_kernel<<<gc, dim3(256), 0, stream>>>(H, Wdt, bd, cnt, list, Y, T);

    combine_kernel<<<dim3(T * D_MODEL / 4 / 256), dim3(256), 0, stream>>>(Y, w_slot, out, T);
}

// Round 3
// 656.480 us; speedup vs baseline: 1.0315x; 1.0315x over previous
//
#include <hip/hip_runtime.h>

typedef float floatx4 __attribute__((ext_vector_type(4)));
typedef __bf16 bf16x2 __attribute__((ext_vector_type(2)));
typedef __bf16 bf16x4 __attribute__((ext_vector_type(4)));
typedef __bf16 bf16x8 __attribute__((ext_vector_type(8)));

#define D_MODEL 1024
#define D_FF 4096
#define NE 8

// ---- async global->LDS, 16B per lane. LDS dest must be lane-linear. ----
__device__ __forceinline__ void gload16(const void* g, void* l) {
    __builtin_amdgcn_global_load_lds(
        (const __attribute__((address_space(1))) void*)g,
        (__attribute__((address_space(3))) void*)l, 16, 0, 0);
}

// Swizzled 32-k subtile: rows x 32 k (bf16). Granule (16B = 8 elems) for
// (row, q) lives at element offset row*32 + ((q ^ ((row>>2)&3))<<3).
__device__ __forceinline__ int frag_off(int row, int q) {
    return row * 32 + ((q ^ ((row >> 2) & 3)) << 3);
}

// pack two fp32 -> one dword of two bf16 (lo = first arg)
__device__ __forceinline__ unsigned int pk(float lo, float hi) {
    union { bf16x2 v; unsigned int u; } c;
    c.v = bf16x2{(__bf16)lo, (__bf16)hi};
    return c.u;
}

// ---- 64x64 fp32->bf16 transpose-convert tile body (LDS scratch tp[64*33]) --
// src: [K][N] fp32 at (kb, nb); dst: [N][K] bf16 at (nb, kb). All threads run.
__device__ __forceinline__ void transpose_tile(
    const float* __restrict__ src, __bf16* __restrict__ dst,
    int K, int N, unsigned int* tp, int tid)
{
    const int p  = tid >> 3;          // k-pair 0..31 (rows 2p, 2p+1)
    const int ci = tid & 7;           // col quad 0..7
    const float* s0 = src + (size_t)(2 * p) * N + 4 * ci;
    float4 r0a = *(const float4*)(s0);
    float4 r0b = *(const float4*)(s0 + 32);
    float4 r1a = *(const float4*)(s0 + N);
    float4 r1b = *(const float4*)(s0 + N + 32);

    unsigned int* w0 = &tp[(4 * ci) * 33 + p];
    w0[0]  = pk(r0a.x, r1a.x);
    w0[33] = pk(r0a.y, r1a.y);
    w0[66] = pk(r0a.z, r1a.z);
    w0[99] = pk(r0a.w, r1a.w);
    unsigned int* w1 = &tp[(4 * ci + 32) * 33 + p];
    w1[0]  = pk(r0b.x, r1b.x);
    w1[33] = pk(r0b.y, r1b.y);
    w1[66] = pk(r0b.z, r1b.z);
    w1[99] = pk(r0b.w, r1b.w);
    __syncthreads();

    const int r = tid >> 2;           // output n-row 0..63
    const int q = tid & 3;            // quarter of the 64-elem k-row
    const unsigned int* rp = &tp[r * 33 + q * 8];
    uint4 oa = {rp[0], rp[1], rp[2], rp[3]};
    uint4 ob = {rp[4], rp[5], rp[6], rp[7]};
    __bf16* drow = dst + (size_t)r * K + q * 16;
    *(uint4*)(drow)     = oa;
    *(uint4*)(drow + 8) = ob;
}

// ---------------- fused router + Wg/Wu transpose-convert + x convert ---------
// blocks [0,8192): Wg, [8192,16384): Wu, [16384,17408): x, [17408,17408+T/4): router
__global__ __launch_bounds__(256) void routerprep_kernel(
    const float* __restrict__ Wg, const float* __restrict__ Wu,
    const float* __restrict__ x, const float* __restrict__ Wr,
    const float* __restrict__ br,
    __bf16* __restrict__ Wgt, __bf16* __restrict__ Wut, __bf16* __restrict__ Xb,
    int* __restrict__ cnt, int* __restrict__ list, float* __restrict__ w_slot,
    int T)
{
    const int bid = blockIdx.x;
    const int tid = threadIdx.x;

    if (bid >= 17408) {
        // -------- router: 4 tokens per block, 1 wave each --------
        int wv = tid >> 6;
        int lane = tid & 63;
        int t = (bid - 17408) * 4 + wv;
        if (t >= T) return;
        const float* xp = x + (size_t)t * D_MODEL;
        float acc[8] = {0.f,0.f,0.f,0.f,0.f,0.f,0.f,0.f};
#pragma unroll
        for (int i = 0; i < 16; ++i) {
            int d = i * 64 + lane;
            float xv = xp[d];
            float4 w0 = *(const float4*)(Wr + d * 8);
            float4 w1 = *(const float4*)(Wr + d * 8 + 4);
            acc[0] += xv * w0.x; acc[1] += xv * w0.y;
            acc[2] += xv * w0.z; acc[3] += xv * w0.w;
            acc[4] += xv * w1.x; acc[5] += xv * w1.y;
            acc[6] += xv * w1.z; acc[7] += xv * w1.w;
        }
#pragma unroll
        for (int off = 32; off >= 1; off >>= 1) {
#pragma unroll
            for (int e = 0; e < 8; ++e)
                acc[e] += __shfl_down(acc[e], off, 64);
        }
        if (lane == 0) {
            float l[8];
#pragma unroll
            for (int e = 0; e < 8; ++e) l[e] = acc[e] + br[e];
            int i0 = 0; float v0 = l[0];
#pragma unroll
            for (int e = 1; e < 8; ++e) if (l[e] > v0) { v0 = l[e]; i0 = e; }
            int i1 = -1; float v1 = -3.4e38f;
#pragma unroll
            for (int e = 0; e < 8; ++e) if (e != i0 && l[e] > v1) { v1 = l[e]; i1 = e; }
            float ex = __expf(v1 - v0);
            float w0 = 1.f / (1.f + ex);
            float w1 = ex / (1.f + ex);
            int p0 = atomicAdd(&cnt[i0], 1);
            list[i0 * T + p0] = 2 * t;
            int p1 = atomicAdd(&cnt[i1], 1);
            list[i1 * T + p1] = 2 * t + 1;
            w_slot[2 * t]     = w0;
            w_slot[2 * t + 1] = w1;
        }
        return;
    }

    if (bid >= 16384) {
        // -------- x fp32 -> bf16 --------
        int base = (bid - 16384) * 2048 + tid * 8;
        float4 v0 = *(const float4*)(x + base);
        float4 v1 = *(const float4*)(x + base + 4);
        bf16x8 o = {(__bf16)v0.x, (__bf16)v0.y, (__bf16)v0.z, (__bf16)v0.w,
                    (__bf16)v1.x, (__bf16)v1.y, (__bf16)v1.z, (__bf16)v1.w};
        *(bf16x8*)(Xb + base) = o;
        return;
    }

    // -------- Wg / Wu transpose-convert (64x64 tiles) --------
    __shared__ unsigned int tp[64 * 33];
    const int tensor = bid >> 13;
    const int rem = bid & 8191;
    const int e = rem >> 10;
    const int tile = rem & 1023;
    const float* src = (tensor == 0) ? Wg : Wu;
    __bf16* dst = (tensor == 0) ? Wgt : Wut;
    const int K = 1024, N = 4096;
    const int kb = (tile & 15) << 6, nb = (tile >> 4) << 6;
    src += (size_t)e * K * N + (size_t)kb * N + nb;
    dst += (size_t)e * K * N + (size_t)nb * K + kb;
    transpose_tile(src, dst, K, N, tp, tid);
}

// ---------------- gate+up GEMM: 128x64 tile, BK=64, 3 blocks/CU --------------
// Extra grid plane blockIdx.z == NE: Wd fp32->bf16 transpose overlay (runs in
// gateup's idle CU slots; down launches after gateup so Wdt is complete).
__global__ __launch_bounds__(256, 3) void gateup3_kernel(
    const __bf16* __restrict__ Xb, const __bf16* __restrict__ Wgt,
    const __bf16* __restrict__ Wut, const float* __restrict__ bg,
    const float* __restrict__ bu, const int* __restrict__ cnt,
    const int* __restrict__ list, __bf16* __restrict__ H,
    const float* __restrict__ Wd, __bf16* __restrict__ Wdt, int T)
{
    __shared__ __bf16 ldsA[8192];    // 2 subtiles of 128x32 (16 KB)
    __shared__ __bf16 ldsBg[4096];   // 2 subtiles of 64x32
    __shared__ __bf16 ldsBu[4096];
    __shared__ int s_entry[128];

    const int tid = threadIdx.x;

    if (blockIdx.z == NE) {
        // -------- Wd transpose-convert overlay: 8 tiles per block --------
        unsigned int* tp = (unsigned int*)ldsA;   // 8448 B <= 16384 B
        const int bid2 = blockIdx.y * gridDim.x + blockIdx.x;   // 0..1023
        const int K = 4096, N = 1024;
#pragma unroll 1
        for (int i = 0; i < 8; ++i) {
            if (i) __syncthreads();   // protect tp reuse across tiles
            int tile = bid2 * 8 + i;  // 0..8191
            int e = tile >> 10, tt = tile & 1023;
            int kb = (tt & 63) << 6, nb = (tt >> 6) << 6;
            const float* src = Wd + (size_t)e * K * N + (size_t)kb * N + nb;
            __bf16* dst = Wdt + (size_t)e * K * N + (size_t)nb * K + kb;
            transpose_tile(src, dst, K, N, tp, tid);
        }
        return;
    }

    const int e  = blockIdx.z;
    const int m0 = blockIdx.y * 128;
    const int n0 = blockIdx.x * 64;
    const int count = cnt[e];
    if (m0 >= count) return;

    if (tid < 128) {
        int r = m0 + tid;
        s_entry[tid] = (r < count) ? list[e * T + r] : list[e * T];
    }
    __syncthreads();

    // A staging: 4 granules/thread. p -> subtile s=p>>9, row=(p&511)>>2,
    // slot j=p&3, src granule g=j^((row>>2)&3). LDS dest byte = p*16 (linear).
    const __bf16* asrc[4]; char* adst[4];
#pragma unroll
    for (int i = 0; i < 4; ++i) {
        int p = i * 256 + tid;
        int s = p >> 9;
        int row = (p & 511) >> 2, j = p & 3;
        int g = j ^ ((row >> 2) & 3);
        asrc[i] = Xb + (size_t)(s_entry[row] >> 1) * D_MODEL + s * 32 + g * 8;
        adst[i] = (char*)ldsA + p * 16;
    }
    // B staging: 2 granules/thread per tensor.
    const __bf16* gsrc[2]; const __bf16* usrc[2]; char* gdst[2]; char* udst[2];
#pragma unroll
    for (int i = 0; i < 2; ++i) {
        int p = i * 256 + tid;
        int s = p >> 8;
        int row = (p & 255) >> 2, j = p & 3;
        int g = j ^ ((row >> 2) & 3);
        gsrc[i] = Wgt + ((size_t)e * D_FF + n0 + row) * D_MODEL + s * 32 + g * 8;
        usrc[i] = Wut + ((size_t)e * D_FF + n0 + row) * D_MODEL + s * 32 + g * 8;
        gdst[i] = (char*)ldsBg + p * 16;
        udst[i] = (char*)ldsBu + p * 16;
    }

    const int wv = tid >> 6, lane = tid & 63;
    const int wm = wv >> 1, wn = wv & 1;
    const int q = lane >> 4, ln = lane & 15;
    int aoff[4], boff[2];
#pragma unroll
    for (int i = 0; i < 4; ++i) aoff[i] = frag_off(wm * 64 + i * 16 + ln, q);
#pragma unroll
    for (int i = 0; i < 2; ++i) boff[i] = frag_off(wn * 32 + i * 16 + ln, q);

    floatx4 accg[4][2] = {};
    floatx4 accu[4][2] = {};

    for (int k0 = 0; k0 < D_MODEL; k0 += 64) {
#pragma unroll
        for (int i = 0; i < 4; ++i) gload16(asrc[i] + k0, adst[i]);
#pragma unroll
        for (int i = 0; i < 2; ++i) {
            gload16(gsrc[i] + k0, gdst[i]);
            gload16(usrc[i] + k0, udst[i]);
        }
        __syncthreads();

#pragma unroll
        for (int s = 0; s < 2; ++s) {
            bf16x8 af[4], bgf[2], buf[2];
#pragma unroll
            for (int i = 0; i < 4; ++i) af[i]  = *(const bf16x8*)&ldsA[s * 4096 + aoff[i]];
#pragma unroll
            for (int i = 0; i < 2; ++i) bgf[i] = *(const bf16x8*)&ldsBg[s * 2048 + boff[i]];
#pragma unroll
            for (int i = 0; i < 2; ++i) buf[i] = *(const bf16x8*)&ldsBu[s * 2048 + boff[i]];
#pragma unroll
            for (int mi = 0; mi < 4; ++mi)
#pragma unroll
                for (int ni = 0; ni < 2; ++ni) {
                    accg[mi][ni] = __builtin_amdgcn_mfma_f32_16x16x32_bf16(af[mi], bgf[ni], accg[mi][ni], 0, 0, 0);
                    accu[mi][ni] = __builtin_amdgcn_mfma_f32_16x16x32_bf16(af[mi], buf[ni], accu[mi][ni], 0, 0, 0);
                }
        }
        __syncthreads();
    }

#pragma unroll
    for (int ni = 0; ni < 2; ++ni) {
        int col = n0 + wn * 32 + ni * 16 + ln;
        float bgv = bg[e * D_FF + col];
        float buv = bu[e * D_FF + col];
#pragma unroll
        for (int mi = 0; mi < 4; ++mi) {
            int lrow0 = wm * 64 + mi * 16 + q * 4;
#pragma unroll
            for (int r = 0; r < 4; ++r) {
                int lr = lrow0 + r;
                if (m0 + lr < count) {
                    int entry = s_entry[lr];
                    float g = accg[mi][ni][r] + bgv;
                    float u = accu[mi][ni][r] + buv;
                    float h = g / (1.f + __expf(-g)) * u;
                    H[(size_t)entry * D_FF + col] = (__bf16)h;
                }
            }
        }
    }
}

// ---------------- down GEMM: 128x128, BK=64, K-split x4 ----------------------
__global__ __launch_bounds__(256, 3) void down3_kernel(
    const __bf16* __restrict__ H, const __bf16* __restrict__ Wdt,
    const float* __restrict__ bd, const int* __restrict__ cnt,
    const int* __restrict__ list, float* __restrict__ Y, int T)
{
    const int e  = blockIdx.z >> 2;
    const int kc = blockIdx.z & 3;
    const int m0 = blockIdx.y * 128;
    const int n0 = blockIdx.x * 128;
    const int count = cnt[e];
    if (m0 >= count) return;

    __shared__ __bf16 ldsA[8192];    // 2 subtiles of 128x32
    __shared__ __bf16 ldsB[8192];
    __shared__ int s_entry[128];

    const int tid = threadIdx.x;
    if (tid < 128) {
        int r = m0 + tid;
        s_entry[tid] = (r < count) ? list[e * T + r] : list[e * T];
    }
    __syncthreads();

    const int kbase = kc * (D_FF / 4);
    const __bf16* asrc[4]; const __bf16* bsrc[4];
    char* adst[4]; char* bdst[4];
#pragma unroll
    for (int i = 0; i < 4; ++i) {
        int p = i * 256 + tid;
        int s = p >> 9;
        int row = (p & 511) >> 2, j = p & 3;
        int g = j ^ ((row >> 2) & 3);
        asrc[i] = H + (size_t)s_entry[row] * D_FF + kbase + s * 32 + g * 8;
        bsrc[i] = Wdt + ((size_t)e * D_MODEL + n0 + row) * D_FF + kbase + s * 32 + g * 8;
        adst[i] = (char*)ldsA + p * 16;
        bdst[i] = (char*)ldsB + p * 16;
    }

    const int wv = tid >> 6, lane = tid & 63;
    const int wm = wv >> 1, wn = wv & 1;
    const int q = lane >> 4, ln = lane & 15;
    int aoff[4], boff[4];
#pragma unroll
    for (int i = 0; i < 4; ++i) {
        aoff[i] = frag_off(wm * 64 + i * 16 + ln, q);
        boff[i] = frag_off(wn * 64 + i * 16 + ln, q);
    }

    floatx4 acc[4][4] = {};

    for (int k0 = 0; k0 < D_FF / 4; k0 += 64) {
#pragma unroll
        for (int i = 0; i < 4; ++i) {
            gload16(asrc[i] + k0, adst[i]);
            gload16(bsrc[i] + k0, bdst[i]);
        }
        __syncthreads();

#pragma unroll
        for (int s = 0; s < 2; ++s) {
            bf16x8 af[4], bf[4];
#pragma unroll
            for (int i = 0; i < 4; ++i) af[i] = *(const bf16x8*)&ldsA[s * 4096 + aoff[i]];
#pragma unroll
            for (int i = 0; i < 4; ++i) bf[i] = *(const bf16x8*)&ldsB[s * 4096 + boff[i]];
#pragma unroll
            for (int mi = 0; mi < 4; ++mi)
#pragma unroll
                for (int ni = 0; ni < 4; ++ni)
                    acc[mi][ni] = __builtin_amdgcn_mfma_f32_16x16x32_bf16(af[mi], bf[ni], acc[mi][ni], 0, 0, 0);
        }
        __syncthreads();
    }

    const size_t kc_off = (size_t)kc * 2 * T * D_MODEL;
#pragma unroll
    for (int ni = 0; ni < 4; ++ni) {
        int col = n0 + wn * 64 + ni * 16 + ln;
        float bdv = (kc == 0) ? bd[e * D_MODEL + col] : 0.f;
#pragma unroll
        for (int mi = 0; mi < 4; ++mi) {
            int lrow0 = wm * 64 + mi * 16 + q * 4;
#pragma unroll
            for (int r = 0; r < 4; ++r) {
                int lr = lrow0 + r;
                if (m0 + lr < count) {
                    int entry = s_entry[lr];
                    Y[kc_off + (size_t)entry * D_MODEL + col] = acc[mi][ni][r] + bdv;
                }
            }
        }
    }
}

// ---------------- combine: out[t] = w0*sum_kc Y[kc][2t] + w1*sum_kc Y[kc][2t+1]
__global__ __launch_bounds__(256) void combine_kernel(
    const float* __restrict__ Y, const float* __restrict__ w_slot,
    float* __restrict__ out, int T)
{
    int idx = blockIdx.x * 256 + threadIdx.x;      // over T*D/4
    int t = idx >> 8;                               // D/4 = 256
    const float4* Y4 = (const float4*)Y;
    size_t r0 = (size_t)(2 * t) * 256 + (idx & 255);
    size_t r1 = r0 + 256;
    size_t ks = (size_t)2 * T * 256;
    float4 a = Y4[r0], b = Y4[r1];
#pragma unroll
    for (int kc = 1; kc < 4; ++kc) {
        float4 va = Y4[r0 + kc * ks], vb = Y4[r1 + kc * ks];
        a.x += va.x; a.y += va.y; a.z += va.z; a.w += va.w;
        b.x += vb.x; b.y += vb.y; b.z += vb.z; b.w += vb.w;
    }
    float w0 = w_slot[2 * t], w1 = w_slot[2 * t + 1];
    float4 o = {w0 * a.x + w1 * b.x, w0 * a.y + w1 * b.y,
                w0 * a.z + w1 * b.z, w0 * a.w + w1 * b.w};
    ((float4*)out)[idx] = o;
}

// ============================================================================
extern "C" void kernel_launch(void* const* d_in, const int* in_sizes, int n_in,
                              void* d_out, int out_size, void* d_ws, size_t ws_size,
                              hipStream_t stream) {
    const float* x  = (const float*)d_in[0];
    const float* Wr = (const float*)d_in[1];
    const float* br = (const float*)d_in[2];
    const float* Wg = (const float*)d_in[3];
    const float* bg = (const float*)d_in[4];
    const float* Wu = (const float*)d_in[5];
    const float* bu = (const float*)d_in[6];
    const float* Wd = (const float*)d_in[7];
    const float* bd = (const float*)d_in[8];
    float* out = (float*)d_out;
    const int T = in_sizes[0] / D_MODEL;   // 2048

    char* ws = (char*)d_ws;
    size_t off = 256;
    int*   cnt    = (int*)ws;
    int*   list   = (int*)(ws + off);              off += (size_t)NE * T * 4;
    float* w_slot = (float*)(ws + off);            off += (size_t)2 * T * 4;
    off = (off + 1023) & ~(size_t)1023;
    __bf16* Xb  = (__bf16*)(ws + off);             off += (size_t)T * D_MODEL * 2;
    __bf16* H   = (__bf16*)(ws + off);             off += (size_t)2 * T * D_FF * 2;
    __bf16* Wgt = (__bf16*)(ws + off);
    float*  Y   = (float*)(ws + off);              // aliases Wgt (dead after gateup)
    off += (size_t)NE * D_MODEL * D_FF * 2;        // 67.1 MB == Y's 67.1 MB (kc=4)
    __bf16* Wut = (__bf16*)(ws + off);             off += (size_t)NE * D_MODEL * D_FF * 2;
    __bf16* Wdt = (__bf16*)(ws + off);             off += (size_t)NE * D_FF * D_MODEL * 2;

    hipMemsetAsync(cnt, 0, 256, stream);

    // router + Wg/Wu transpose-convert + x convert, fused
    routerprep_kernel<<<dim3(17408 + T / 4), dim3(256), 0, stream>>>(
        Wg, Wu, x, Wr, br, Wgt, Wut, Xb, cnt, list, w_slot, T);

    // gate+up GEMM with Wd-conversion overlay plane (z == NE)
    dim3 gb(D_FF / 64, (T + 127) / 128, NE + 1);
    gateup3_kernel<<<gb, dim3(256), 0, stream>>>(
        Xb, Wgt, Wut, bg, bu, cnt, list, H, Wd, Wdt, T);

    dim3 gc(D_MODEL / 128, (T + 127) / 128, NE * 4);
    down3_kernel<<<gc, dim3(256), 0, stream>>>(H, Wdt, bd, cnt, list, Y, T);

    combine_kernel<<<dim3(T * D_MODEL / 4 / 256), dim3(256), 0, stream>>>(Y, w_slot, out, T);
}